// Round 11
// baseline (147.586 us; speedup 1.0000x reference)
//
#include <hip/hip_runtime.h>
#include <math.h>

#define MM 4
#define BB 128
#define CC 10
#define KK 32
#define FF 512
#define HH 512
#define NP 320            // C*K rows per model
#define OUTW 5120         // F*C

using bf16x8 = __attribute__((ext_vector_type(8))) short;
using f32x4  = __attribute__((ext_vector_type(4))) float;

__device__ __forceinline__ unsigned short f2bf(float f) {
    unsigned int u = __float_as_uint(f);
    u += 0x7FFFu + ((u >> 16) & 1u);          // round-to-nearest-even
    return (unsigned short)(u >> 16);
}

// ---------------- unified pipelined MFMA GEMM tile (round-6 proven core) ----
// Waves WRxWC, per-wave fragments IxJ. TR=WR*I*16 (<=64), TC=WC*J*16 (==64).
// Single-step lookahead: FETCH(k+1) -> MFMA(k) -> WRITE(k+1) -> barrier.
// EPI 0: bf16( relu((acc + onehot_rank1)*s + bias) * auxr )    (fc1 -> A2)
// EPI 1: psum write + pn_part slot write (WR==1, TR==32)       (fc2)
// EPI 2: spin dep_ticket, zn/cr slot writes (atomic psum read) (z-GEMM)
// ASRC 0: bf16 A[row][512];  ASRC 2: f32 Af32[row%NP][512] * ascale[m][522]
// BSRC 0: bf16 Bt[col][512]; BSRC 1: f32 W[k][NCOLS] k-major gather
template<int EPI, int ASRC, int BSRC, int WR, int WC, int I, int J,
         int KSTEPS, int RPM, int NCOLS>
__device__ __forceinline__ void gemm_tile(
    const int bx, const int by,
    const unsigned short* __restrict__ Abf, const float* __restrict__ Af32,
    const float* __restrict__ ascale,
    const unsigned short* __restrict__ Btbf, const float* __restrict__ Bf32,
    const float* __restrict__ s, const float* __restrict__ bias,
    const float* __restrict__ auxr, void* __restrict__ outv,
    float* __restrict__ auxw,
    const float* __restrict__ ohW, const float* __restrict__ ohR,
    unsigned int* dep_ticket, unsigned int dep_count,
    unsigned short* smem)
{
    constexpr int TR = WR * I * 16;
    constexpr int TC = WC * J * 16;
    static_assert(TR <= 64 && TC == 64, "staging geometry");
    constexpr int BUFE = (TR + TC) * 32;
    const int t = threadIdx.x;
    const int lane = t & 63;
    const int w = t >> 6;
    const int wr = w / WC, wc = w % WC;
    const int l15 = lane & 15, l4 = lane >> 4;
    const int rowT = by * TR, colT = bx * TC;
    const int m = rowT / RPM;

    // ---- A staging setup (1 uint4/thread, guard if TR<64) ----
    constexpr bool AGUARD = (TR * 4 < 256);
    const bool aact = !AGUARD || (t < TR * 4);
    const int asrow = t >> 2, ag = t & 3;
    const int stA = asrow * 32 + ((ag ^ ((asrow >> 1) & 3)) * 8);
    const unsigned short* gA = nullptr;
    const float* gAf = nullptr;
    const float* scp = nullptr;
    if constexpr (ASRC == 0) {
        if (aact) gA = Abf + (size_t)(rowT + asrow) * 512 + ag * 8;
    } else {
        static_assert(TR == 64, "ASRC2 needs TR==64");
        gAf = Af32 + (size_t)((rowT % NP) + asrow) * 512 + ag * 8;
        scp = ascale + (size_t)m * 522 + ag * 8;
    }
    // ---- B staging setup ----
    const int bsrow = t >> 2, bg = t & 3;        // BSRC0
    const int stB0 = bsrow * 32 + ((bg ^ ((bsrow >> 1) & 3)) * 8);
    const int bcol = t & 63, bkg = t >> 6;       // BSRC1
    const int stB1 = bcol * 32 + ((bkg ^ ((bcol >> 1) & 3)) * 8);
    const unsigned short* gB = nullptr;
    if constexpr (BSRC == 0)
        gB = Btbf + (size_t)(colT + bsrow) * 512 + bg * 8;

    int offA[I], offB[J];
#pragma unroll
    for (int i = 0; i < I; ++i) {
        const int rA = wr * (I * 16) + i * 16 + l15;
        offA[i] = rA * 32 + ((l4 ^ ((rA >> 1) & 3)) * 8);
    }
#pragma unroll
    for (int j = 0; j < J; ++j) {
        const int rB = wc * (J * 16) + j * 16 + l15;
        offB[j] = rB * 32 + ((l4 ^ ((rB >> 1) & 3)) * 8);
    }

    f32x4 acc[I][J];
#pragma unroll
    for (int i = 0; i < I; ++i)
#pragma unroll
        for (int j = 0; j < J; ++j) acc[i][j] = (f32x4){0.f, 0.f, 0.f, 0.f};

    // register staging state
    uint4 ra, rb;
    float4 nf0, nf1, ns0, ns1;
    float rbf[8];

#define FETCH(KS)                                                              \
    {                                                                          \
        const int k0_ = (KS) * 32;                                             \
        if constexpr (ASRC == 0) {                                             \
            if (aact) ra = *(const uint4*)(gA + k0_);                          \
        } else {                                                               \
            nf0 = *(const float4*)(gAf + k0_);                                 \
            nf1 = *(const float4*)(gAf + k0_ + 4);                             \
            ns0 = *(const float4*)(scp + k0_);                                 \
            ns1 = *(const float4*)(scp + k0_ + 4);                             \
        }                                                                      \
        if constexpr (BSRC == 0) {                                             \
            rb = *(const uint4*)(gB + k0_);                                    \
        } else {                                                               \
            _Pragma("unroll")                                                  \
            for (int q = 0; q < 8; ++q) {                                      \
                const int gk = k0_ + bkg * 8 + q;                              \
                rbf[q] = Bf32[(size_t)gk * NCOLS + colT + bcol];               \
            }                                                                  \
        }                                                                      \
    }

#define WRITE(KS, BUF)                                                         \
    {                                                                          \
        unsigned short* As_ = smem + (BUF) * BUFE;                             \
        unsigned short* Bs_ = As_ + TR * 32;                                   \
        if constexpr (ASRC == 0) {                                             \
            if (aact) *(uint4*)(As_ + stA) = ra;                               \
        } else {                                                               \
            union { unsigned short us[8]; uint4 q4; } o;                       \
            float vv[8] = {nf0.x, nf0.y, nf0.z, nf0.w,                         \
                           nf1.x, nf1.y, nf1.z, nf1.w};                        \
            float ss[8] = {ns0.x, ns0.y, ns0.z, ns0.w,                         \
                           ns1.x, ns1.y, ns1.z, ns1.w};                        \
            _Pragma("unroll")                                                  \
            for (int q = 0; q < 8; ++q) o.us[q] = f2bf(vv[q] * ss[q]);         \
            *(uint4*)(As_ + stA) = o.q4;                                       \
        }                                                                      \
        if constexpr (BSRC == 0) {                                             \
            *(uint4*)(Bs_ + stB0) = rb;                                        \
        } else {                                                               \
            union { unsigned short us[8]; uint4 q4; } ob;                      \
            _Pragma("unroll")                                                  \
            for (int q = 0; q < 8; ++q) ob.us[q] = f2bf(rbf[q]);               \
            *(uint4*)(Bs_ + stB1) = ob.q4;                                     \
        }                                                                      \
    }

    // prologue
    FETCH(0);
    WRITE(0, 0);
    __syncthreads();

#pragma unroll 1
    for (int ks = 0; ks < KSTEPS; ++ks) {
        const int cur = ks & 1;
        if (ks + 1 < KSTEPS) FETCH(ks + 1);
        const unsigned short* As_ = smem + cur * BUFE;
        const unsigned short* Bs_ = As_ + TR * 32;
        bf16x8 af[I], bfv[J];
#pragma unroll
        for (int i = 0; i < I; ++i) af[i] = *(const bf16x8*)(As_ + offA[i]);
#pragma unroll
        for (int j = 0; j < J; ++j) bfv[j] = *(const bf16x8*)(Bs_ + offB[j]);
#pragma unroll
        for (int i = 0; i < I; ++i)
#pragma unroll
            for (int j = 0; j < J; ++j)
                acc[i][j] = __builtin_amdgcn_mfma_f32_16x16x32_bf16(
                    af[i], bfv[j], acc[i][j], 0, 0, 0);
        if (ks + 1 < KSTEPS) {
            WRITE(ks + 1, cur ^ 1);
            __syncthreads();
        }
    }
#undef FETCH
#undef WRITE

    if constexpr (EPI == 0) {
#pragma unroll
        for (int j = 0; j < J; ++j) {
            const int col = colT + wc * (J * 16) + j * 16 + l15;
            const float sv = s[(size_t)m * NCOLS + col];
            const float bv = bias[(size_t)m * NCOLS + col];
            const float rv = auxr[(size_t)m * NCOLS + col];
#pragma unroll
            for (int i = 0; i < I; ++i)
#pragma unroll
                for (int ir = 0; ir < 4; ++ir) {
                    const int row = rowT + wr * (I * 16) + i * 16 + l4 * 4 + ir;
                    const int cn = (row % NP) >> 5;          // class of this row
                    const float term = ohR[(size_t)m * 522 + 512 + cn] *
                                       ohW[(size_t)(512 + cn) * NCOLS + col];
                    float v = fmaxf((acc[i][j][ir] + term) * sv + bv, 0.f) * rv;
                    ((unsigned short*)outv)[(size_t)row * NCOLS + col] = f2bf(v);
                }
        }
    } else if constexpr (EPI == 1) {
        // block rows = one (m,c) class group (TR==32); psum in (m,c,f) order
        static_assert(WR == 1 && I == 2 && J == 1, "EPI1 geometry");
        const int mq = rowT / NP;
        const int c = (rowT % NP) / KK;
        const int mc = mq * CC + c;
        const int col = colT + wc * 16 + l15;
        const float sv = s[(size_t)mq * NCOLS + col];
        const float bv = bias[(size_t)mq * NCOLS + col];
        float cs = 0.f, sq = 0.f;
#pragma unroll
        for (int i = 0; i < I; ++i)
#pragma unroll
            for (int ir = 0; ir < 4; ++ir) {
                float v = acc[i][0][ir] * sv + bv;
                cs += v;
                sq += v * v;
            }
        cs += __shfl_xor(cs, 16, 64);
        cs += __shfl_xor(cs, 32, 64);
        if (l4 == 0) ((float*)outv)[(size_t)mc * FF + col] = cs;
#pragma unroll
        for (int off = 1; off < 64; off <<= 1) sq += __shfl_xor(sq, off, 64);
        if (lane == 0) auxw[mc * 32 + bx * 4 + w] = sq;
    } else {
        // EPI 2: wait for fc2's psum, then per-(row,class) zn/cr slot write
        static_assert(WR == 2 && WC == 2 && J == 2, "EPI2 geometry");
        if (dep_ticket != nullptr) {
            __syncthreads();
            if (t == 0) {
                while (__hip_atomic_load(dep_ticket, __ATOMIC_ACQUIRE,
                                         __HIP_MEMORY_SCOPE_AGENT) < dep_count)
                    __builtin_amdgcn_s_sleep(2);
            }
            __syncthreads();
        }
        const int cb = colT >> 9;                    // class of this col tile
        const int slot = ((bx & 7) << 1) | wc;
        float sv[J], pv[J];
#pragma unroll
        for (int j = 0; j < J; ++j) {
            const int col = colT + wc * (J * 16) + j * 16 + l15;   // (c,f) order
            sv[j] = s[(size_t)m * NCOLS + (col & 511) * 10 + (col >> 9)];
            pv[j] = __hip_atomic_load((float*)&bias[(size_t)m * NCOLS + col],
                                      __ATOMIC_RELAXED, __HIP_MEMORY_SCOPE_AGENT);
        }
        float* dst = (float*)outv;
#pragma unroll
        for (int i = 0; i < I; ++i)
#pragma unroll
            for (int ir = 0; ir < 4; ++ir) {
                const int row = rowT + wr * (I * 16) + i * 16 + l4 * 4 + ir;
                float znv = 0.f, crv = 0.f;
#pragma unroll
                for (int j = 0; j < J; ++j) {
                    float v = acc[i][j][ir] * sv[j];
                    znv += v * v;
                    crv += v * pv[j];
                }
#pragma unroll
                for (int off = 1; off < 16; off <<= 1) {
                    znv += __shfl_xor(znv, off, 64);
                    crv += __shfl_xor(crv, off, 64);
                }
                if (l15 == 0) {
                    float2 o = {znv, crv};
                    *(float2*)(dst + ((size_t)(row * CC + cb) * 16 + slot) * 2) = o;
                }
            }
    }
}

// ====== K1: fc1 GEMM + W_lw transpose + xr build + ticket reset ======
__global__ __launch_bounds__(256) void k_phase1(
    const float* __restrict__ noise, const float* __restrict__ r1,
    const float* __restrict__ W1, const float* __restrict__ s1,
    const float* __restrict__ b1, const float* __restrict__ r2,
    const float* __restrict__ W_lw, const float* __restrict__ x,
    const float* __restrict__ r_lw,
    unsigned short* __restrict__ A2, unsigned short* __restrict__ Wlwt,
    unsigned short* __restrict__ xr, unsigned int* __restrict__ tickets)
{
    __shared__ __align__(16) unsigned short smem[8192];   // 16 KiB
    const int b = blockIdx.x;
    const int t = threadIdx.x;
    if (b < 160) {
        // fc1: A = noise*r1 (onehot as rank-1 in epilogue), B = W1 f32 k-major
        gemm_tile<0, 2, 1, 2, 2, 2, 2, 16, NP, HH>(
            b % 8, b / 8, nullptr, noise, r1, nullptr, W1,
            s1, b1, r2, (void*)A2, nullptr, W1, r1, nullptr, 0u, smem);
    } else if (b < 800) {
        // W_lw [512][5120] f32 -> Wlwt[(c,f)][512] bf16 (col remap (f,c)->(c,f))
        unsigned short (*T)[65] = (unsigned short (*)[65])smem;
        const int bb = b - 160;
        const int n0 = (bb % 80) * 64, k0 = (bb / 80) * 64;
#pragma unroll
        for (int p = 0; p < 4; ++p) {
            int kk = (t >> 4) + p * 16;
            int nn = (t & 15) * 4;
            float4 v = *(const float4*)(W_lw + (size_t)(k0 + kk) * OUTW + n0 + nn);
            T[nn + 0][kk] = f2bf(v.x);
            T[nn + 1][kk] = f2bf(v.y);
            T[nn + 2][kk] = f2bf(v.z);
            T[nn + 3][kk] = f2bf(v.w);
        }
        __syncthreads();
#pragma unroll
        for (int p = 0; p < 2; ++p) {
            int n = (t >> 3) + p * 32;
            int kg = t & 7;
            union { unsigned short us[8]; uint4 v; } o;
#pragma unroll
            for (int q = 0; q < 8; ++q) o.us[q] = T[n][kg * 8 + q];
            int gn = n0 + n;
            int dr = (gn % 10) * 512 + gn / 10;      // (f,c) -> (c,f)
            *(uint4*)(Wlwt + (size_t)dr * 512 + k0 + kg * 8) = o.v;
        }
    } else {
        // xr [512][512] bf16 = x * r_lw
        const int id = (b - 800) * 256 + t;          // 32768 exact
        const int row = id >> 6, g = id & 63;
        const int mq = row >> 7;
        const float* xp = x + (size_t)row * 512 + g * 8;
        const float* rp = r_lw + (size_t)mq * 512 + g * 8;
        union { unsigned short us[8]; uint4 v; } o;
#pragma unroll
        for (int q = 0; q < 8; ++q) o.us[q] = f2bf(xp[q] * rp[q]);
        *(uint4*)(xr + (size_t)row * 512 + g * 8) = o.v;
        if (b == 800 && t == 0) { tickets[0] = 0u; tickets[1] = 0u; }
    }
}

// ====== K2: fc2 GEMM || z GEMM (epilogue-spin on fc2) || out tail ======
__global__ __launch_bounds__(256) void k_fused2(
    const unsigned short* __restrict__ A2, const float* __restrict__ W2,
    const float* __restrict__ s2, const float* __restrict__ b2,
    float* __restrict__ psum, float* __restrict__ pn_part,
    const unsigned short* __restrict__ xr, const unsigned short* __restrict__ Wlwt,
    const float* __restrict__ s_lw, float* __restrict__ dist_part,
    unsigned int* __restrict__ tickets, float* __restrict__ out)
{
    __shared__ __align__(16) unsigned short smem[8192];   // 16 KiB
    const int blk = blockIdx.x;
    const int t = threadIdx.x;
    if (blk < 320) {
        // fc2: A2 bf16, B = W2 f32 k-major; fused psum/pn_part epilogue
        gemm_tile<1, 0, 1, 1, 4, 2, 1, 16, NP, FF>(
            blk % 8, blk / 8, A2, nullptr, nullptr, nullptr, W2,
            s2, b2, nullptr, (void*)psum, pn_part, nullptr, nullptr,
            nullptr, 0u, smem);
        __syncthreads();
        if (t == 0) {
            __threadfence();
            __hip_atomic_fetch_add(&tickets[0], 1u, __ATOMIC_RELEASE,
                                   __HIP_MEMORY_SCOPE_AGENT);
        }
    } else if (blk < 960) {
        // z-GEMM: main loop needs no psum; epilogue spins on tickets[0]
        const int zb = blk - 320;
        gemm_tile<2, 0, 0, 2, 2, 2, 2, 16, BB, OUTW>(
            zb % 80, zb / 80, xr, nullptr, nullptr, Wlwt, nullptr,
            s_lw, psum, nullptr, (void*)dist_part, nullptr, nullptr, nullptr,
            &tickets[0], 320u, smem);
        __syncthreads();
        if (t == 0) {
            __threadfence();
            __hip_atomic_fetch_add(&tickets[1], 1u, __ATOMIC_RELEASE,
                                   __HIP_MEMORY_SCOPE_AGENT);
        }
    } else {
        // 20 tail blocks: wait for all 640 z blocks, then reduce + exp
        if (t == 0) {
            while (__hip_atomic_load(&tickets[1], __ATOMIC_ACQUIRE,
                                     __HIP_MEMORY_SCOPE_AGENT) < 640u)
                __builtin_amdgcn_s_sleep(8);
        }
        __syncthreads();
        __threadfence();
        const int id = (blk - 960) * 256 + t;        // 5120 exact
        const int c = id % 10;
        const int mc = ((id / 10) >> 7) * 10 + c;
        float zn = 0.f, cr = 0.f;
        const float* dp = dist_part + (size_t)id * 32;
#pragma unroll
        for (int q = 0; q < 16; ++q) {
            zn += __hip_atomic_load((float*)&dp[q * 2], __ATOMIC_RELAXED,
                                    __HIP_MEMORY_SCOPE_AGENT);
            cr += __hip_atomic_load((float*)&dp[q * 2 + 1], __ATOMIC_RELAXED,
                                    __HIP_MEMORY_SCOPE_AGENT);
        }
        float pnv = 0.f;
#pragma unroll
        for (int q = 0; q < 32; ++q)
            pnv += __hip_atomic_load((float*)&pn_part[mc * 32 + q],
                                     __ATOMIC_RELAXED, __HIP_MEMORY_SCOPE_AGENT);
        const float inv = 1.f / (2.f * (float)KK * (float)FF);
        out[id] = expf(-((float)KK * zn - 2.f * cr + pnv) * inv);
    }
}

extern "C" void kernel_launch(void* const* d_in, const int* in_sizes, int n_in,
                              void* d_out, int out_size, void* d_ws, size_t ws_size,
                              hipStream_t stream) {
    const float* x     = (const float*)d_in[0];
    const float* noise = (const float*)d_in[1];
    const float* W_lw  = (const float*)d_in[2];
    const float* r_lw  = (const float*)d_in[3];
    const float* s_lw  = (const float*)d_in[4];
    const float* W1    = (const float*)d_in[5];
    const float* r1    = (const float*)d_in[6];
    const float* s1    = (const float*)d_in[7];
    const float* b1    = (const float*)d_in[8];
    const float* W2    = (const float*)d_in[9];
    const float* r2    = (const float*)d_in[10];
    const float* s2    = (const float*)d_in[11];
    const float* b2    = (const float*)d_in[12];
    float* out = (float*)d_out;

    char* base = (char*)d_ws;
    float* psum          = (float*)(base + 0);                 //    81,920 B
    float* pn_part       = (float*)(base + 81920);             //     5,120 B
    float* dist_part     = (float*)(base + 87040);             //   655,360 B
    unsigned int* tickets= (unsigned int*)(base + 742400);     //       256 B
    unsigned short* A2   = (unsigned short*)(base + 742656);   // 1,310,720 B
    unsigned short* xr   = (unsigned short*)(base + 2053376);  //   524,288 B
    unsigned short* Wlwt = (unsigned short*)(base + 2577664);  // 5,242,880 B

    k_phase1<<<928, 256, 0, stream>>>(noise, r1, W1, s1, b1, r2, W_lw, x, r_lw,
                                      A2, Wlwt, xr, tickets);
    k_fused2<<<980, 256, 0, stream>>>(A2, W2, s2, b2, psum, pn_part,
                                      xr, Wlwt, s_lw, dist_part, tickets, out);
}

// Round 13
// 54.631 us; speedup vs baseline: 2.7015x; 2.7015x over previous
//
#include <hip/hip_runtime.h>
#include <math.h>

#define MM 4
#define BB 128
#define CC 10
#define KK 32
#define FF 512
#define HH 512
#define NP 320            // C*K rows per model
#define OUTW 5120         // F*C

using bf16x8 = __attribute__((ext_vector_type(8))) short;
using f32x4  = __attribute__((ext_vector_type(4))) float;

__device__ __forceinline__ unsigned short f2bf(float f) {
    unsigned int u = __float_as_uint(f);
    u += 0x7FFFu + ((u >> 16) & 1u);          // round-to-nearest-even
    return (unsigned short)(u >> 16);
}

// ---------------- unified pipelined MFMA GEMM tile (round-6 proven core) ----
// Waves WRxWC, per-wave fragments IxJ. TR=WR*I*16 (<=64), TC=WC*J*16 (==64).
// Single-step lookahead: FETCH(k+1) -> MFMA(k) -> WRITE(k+1) -> barrier.
// EPI 0: bf16( relu(acc*s + bias) * auxr )                     (fc1 -> A2)
// EPI 1: psum write + pn_part slot write (WR==1, TR==32)       (fc2)
// EPI 2: zn/cr slot writes into dist_part (WR=WC=I=J=2)        (z-GEMM)
// ASRC 0: bf16 A[row][512];  ASRC 2: f32 Af32[row%NP][512]*ascale, onehot tail
// BSRC 0: bf16 Bt[col][512]; BSRC 1: f32 W[k][NCOLS] k-major gather
template<int EPI, int ASRC, int BSRC, int WR, int WC, int I, int J,
         int KSTEPS, int KREALB, int RPM, int NCOLS>
__device__ __forceinline__ void gemm_tile(
    const int bx, const int by,
    const unsigned short* __restrict__ Abf, const float* __restrict__ Af32,
    const float* __restrict__ ascale,
    const unsigned short* __restrict__ Btbf, const float* __restrict__ Bf32,
    const float* __restrict__ s, const float* __restrict__ bias,
    const float* __restrict__ auxr, void* __restrict__ outv,
    float* __restrict__ auxw, unsigned short* smem)
{
    constexpr int TR = WR * I * 16;
    constexpr int TC = WC * J * 16;
    static_assert(TR <= 64 && TC == 64, "staging geometry");
    constexpr int BUFE = (TR + TC) * 32;
    const int t = threadIdx.x;
    const int lane = t & 63;
    const int w = t >> 6;
    const int wr = w / WC, wc = w % WC;
    const int l15 = lane & 15, l4 = lane >> 4;
    const int rowT = by * TR, colT = bx * TC;
    const int m = rowT / RPM;

    // ---- A staging setup (1 uint4/thread, guard if TR<64) ----
    constexpr bool AGUARD = (TR * 4 < 256);
    const bool aact = !AGUARD || (t < TR * 4);
    const int asrow = t >> 2, ag = t & 3;
    const int stA = asrow * 32 + ((ag ^ ((asrow >> 1) & 3)) * 8);
    const unsigned short* gA = nullptr;
    const float* gAf = nullptr;
    const float* scp = nullptr;
    int cn = 0;
    if constexpr (ASRC == 0) {
        if (aact) gA = Abf + (size_t)(rowT + asrow) * 512 + ag * 8;
    } else {
        static_assert(TR == 64, "ASRC2 needs TR==64");
        gAf = Af32 + (size_t)((rowT % NP) + asrow) * 512 + ag * 8;
        scp = ascale + (size_t)m * 522 + ag * 8;
        cn = ((rowT % NP) + asrow) >> 5;
    }
    // ---- B staging setup ----
    const int bsrow = t >> 2, bg = t & 3;        // BSRC0
    const int stB0 = bsrow * 32 + ((bg ^ ((bsrow >> 1) & 3)) * 8);
    const int bcol = t & 63, bkg = t >> 6;       // BSRC1
    const int stB1 = bcol * 32 + ((bkg ^ ((bcol >> 1) & 3)) * 8);
    const unsigned short* gB = nullptr;
    if constexpr (BSRC == 0)
        gB = Btbf + (size_t)(colT + bsrow) * 512 + bg * 8;

    int offA[I], offB[J];
#pragma unroll
    for (int i = 0; i < I; ++i) {
        const int rA = wr * (I * 16) + i * 16 + l15;
        offA[i] = rA * 32 + ((l4 ^ ((rA >> 1) & 3)) * 8);
    }
#pragma unroll
    for (int j = 0; j < J; ++j) {
        const int rB = wc * (J * 16) + j * 16 + l15;
        offB[j] = rB * 32 + ((l4 ^ ((rB >> 1) & 3)) * 8);
    }

    f32x4 acc[I][J];
#pragma unroll
    for (int i = 0; i < I; ++i)
#pragma unroll
        for (int j = 0; j < J; ++j) acc[i][j] = (f32x4){0.f, 0.f, 0.f, 0.f};

    // register staging state
    uint4 ra, rb;
    float4 nf0, nf1, ns0, ns1;
    float rbf[8];

#define FETCH(KS)                                                              \
    {                                                                          \
        const int k0_ = (KS) * 32;                                             \
        if constexpr (ASRC == 0) {                                             \
            if (aact) ra = *(const uint4*)(gA + k0_);                          \
        } else {                                                               \
            if (k0_ < 512) {                                                   \
                nf0 = *(const float4*)(gAf + k0_);                             \
                nf1 = *(const float4*)(gAf + k0_ + 4);                         \
                ns0 = *(const float4*)(scp + k0_);                             \
                ns1 = *(const float4*)(scp + k0_ + 4);                         \
            }                                                                  \
        }                                                                      \
        if constexpr (BSRC == 0) {                                             \
            rb = *(const uint4*)(gB + k0_);                                    \
        } else {                                                               \
            _Pragma("unroll")                                                  \
            for (int q = 0; q < 8; ++q) {                                      \
                const int gk = k0_ + bkg * 8 + q;                              \
                rbf[q] = (gk < KREALB)                                         \
                    ? Bf32[(size_t)gk * NCOLS + colT + bcol] : 0.f;            \
            }                                                                  \
        }                                                                      \
    }

#define WRITE(KS, BUF)                                                         \
    {                                                                          \
        const int k0_ = (KS) * 32;                                             \
        unsigned short* As_ = smem + (BUF) * BUFE;                             \
        unsigned short* Bs_ = As_ + TR * 32;                                   \
        if constexpr (ASRC == 0) {                                             \
            if (aact) *(uint4*)(As_ + stA) = ra;                               \
        } else {                                                               \
            union { unsigned short us[8]; uint4 q4; } o;                       \
            if (k0_ < 512) {                                                   \
                float vv[8] = {nf0.x, nf0.y, nf0.z, nf0.w,                     \
                               nf1.x, nf1.y, nf1.z, nf1.w};                    \
                float ss[8] = {ns0.x, ns0.y, ns0.z, ns0.w,                     \
                               ns1.x, ns1.y, ns1.z, ns1.w};                    \
                _Pragma("unroll")                                              \
                for (int q = 0; q < 8; ++q) o.us[q] = f2bf(vv[q] * ss[q]);     \
            } else {                                                           \
                _Pragma("unroll")                                              \
                for (int q = 0; q < 8; ++q) {                                  \
                    const int gk = k0_ + ag * 8 + q;                           \
                    float v = (gk < 522 && (gk - 512) == cn)                   \
                        ? ascale[(size_t)m * 522 + gk] : 0.f;                  \
                    o.us[q] = f2bf(v);                                         \
                }                                                              \
            }                                                                  \
            *(uint4*)(As_ + stA) = o.q4;                                       \
        }                                                                      \
        if constexpr (BSRC == 0) {                                             \
            *(uint4*)(Bs_ + stB0) = rb;                                        \
        } else {                                                               \
            union { unsigned short us[8]; uint4 q4; } ob;                      \
            _Pragma("unroll")                                                  \
            for (int q = 0; q < 8; ++q) ob.us[q] = f2bf(rbf[q]);               \
            *(uint4*)(Bs_ + stB1) = ob.q4;                                     \
        }                                                                      \
    }

    // prologue
    FETCH(0);
    WRITE(0, 0);
    __syncthreads();

#pragma unroll 1
    for (int ks = 0; ks < KSTEPS; ++ks) {
        const int cur = ks & 1;
        if (ks + 1 < KSTEPS) FETCH(ks + 1);
        const unsigned short* As_ = smem + cur * BUFE;
        const unsigned short* Bs_ = As_ + TR * 32;
        bf16x8 af[I], bfv[J];
#pragma unroll
        for (int i = 0; i < I; ++i) af[i] = *(const bf16x8*)(As_ + offA[i]);
#pragma unroll
        for (int j = 0; j < J; ++j) bfv[j] = *(const bf16x8*)(Bs_ + offB[j]);
#pragma unroll
        for (int i = 0; i < I; ++i)
#pragma unroll
            for (int j = 0; j < J; ++j)
                acc[i][j] = __builtin_amdgcn_mfma_f32_16x16x32_bf16(
                    af[i], bfv[j], acc[i][j], 0, 0, 0);
        if (ks + 1 < KSTEPS) {
            WRITE(ks + 1, cur ^ 1);
            __syncthreads();
        }
    }
#undef FETCH
#undef WRITE

    if constexpr (EPI == 0) {
#pragma unroll
        for (int j = 0; j < J; ++j) {
            const int col = colT + wc * (J * 16) + j * 16 + l15;
            const float sv = s[(size_t)m * NCOLS + col];
            const float bv = bias[(size_t)m * NCOLS + col];
            const float rv = auxr[(size_t)m * NCOLS + col];
#pragma unroll
            for (int i = 0; i < I; ++i)
#pragma unroll
                for (int ir = 0; ir < 4; ++ir) {
                    const int row = rowT + wr * (I * 16) + i * 16 + l4 * 4 + ir;
                    float v = fmaxf(acc[i][j][ir] * sv + bv, 0.f) * rv;
                    ((unsigned short*)outv)[(size_t)row * NCOLS + col] = f2bf(v);
                }
        }
    } else if constexpr (EPI == 1) {
        // block rows = one (m,c) class group (TR==32); psum in (m,c,f) order
        static_assert(WR == 1 && I == 2 && J == 1, "EPI1 geometry");
        const int mq = rowT / NP;
        const int c = (rowT % NP) / KK;
        const int mc = mq * CC + c;
        const int col = colT + wc * 16 + l15;
        const float sv = s[(size_t)mq * NCOLS + col];
        const float bv = bias[(size_t)mq * NCOLS + col];
        float cs = 0.f, sq = 0.f;
#pragma unroll
        for (int i = 0; i < I; ++i)
#pragma unroll
            for (int ir = 0; ir < 4; ++ir) {
                float v = acc[i][0][ir] * sv + bv;
                cs += v;
                sq += v * v;
            }
        cs += __shfl_xor(cs, 16, 64);
        cs += __shfl_xor(cs, 32, 64);
        if (l4 == 0) ((float*)outv)[(size_t)mc * FF + col] = cs;
#pragma unroll
        for (int off = 1; off < 64; off <<= 1) sq += __shfl_xor(sq, off, 64);
        if (lane == 0) auxw[mc * 32 + bx * 4 + w] = sq;
    } else {
        // EPI 2: dist_part[row][c][slot][2], slot = (bx&7)*2 + wc
        static_assert(WR == 2 && WC == 2 && I == 2 && J == 2, "EPI2 geometry");
        const int cb = colT >> 9;                    // class of this col tile
        const int slot = ((bx & 7) << 1) | wc;
        float sv[J], pv[J];
#pragma unroll
        for (int j = 0; j < J; ++j) {
            const int col = colT + wc * (J * 16) + j * 16 + l15;   // (c,f) order
            sv[j] = s[(size_t)m * NCOLS + (col & 511) * 10 + (col >> 9)];
            pv[j] = bias[(size_t)m * NCOLS + col];   // psum, (c,f)-ordered
        }
        float* dst = (float*)outv;
#pragma unroll
        for (int i = 0; i < I; ++i)
#pragma unroll
            for (int ir = 0; ir < 4; ++ir) {
                const int row = rowT + wr * (I * 16) + i * 16 + l4 * 4 + ir;
                float znv = 0.f, crv = 0.f;
#pragma unroll
                for (int j = 0; j < J; ++j) {
                    float v = acc[i][j][ir] * sv[j];
                    znv += v * v;
                    crv += v * pv[j];
                }
#pragma unroll
                for (int off = 1; off < 16; off <<= 1) {
                    znv += __shfl_xor(znv, off, 64);
                    crv += __shfl_xor(crv, off, 64);
                }
                if (l15 == 0) {
                    float2 o = {znv, crv};
                    *(float2*)(dst + ((size_t)(row * CC + cb) * 16 + slot) * 2) = o;
                }
            }
    }
}

// ====== K1: fc1 GEMM only (critical-path producer for K2) ======
__global__ __launch_bounds__(256) void k_phase1(
    const float* __restrict__ noise, const float* __restrict__ r1,
    const float* __restrict__ W1, const float* __restrict__ s1,
    const float* __restrict__ b1, const float* __restrict__ r2,
    unsigned short* __restrict__ A2)
{
    __shared__ __align__(16) unsigned short smem[8192];   // 16 KiB
    // fc1: A = noise*r1 (+onehot tail step), B = W1 [522][512] f32 k-major
    gemm_tile<0, 2, 1, 2, 2, 2, 2, 17, 522, NP, HH>(
        blockIdx.x % 8, blockIdx.x / 8, nullptr, noise, r1, nullptr, W1,
        s1, b1, r2, (void*)A2, nullptr, smem);
}

// ====== K2: fc2 GEMM (+psum/pn) || W_lw transpose || xr build ======
__global__ __launch_bounds__(256) void k_phase2(
    const unsigned short* __restrict__ A2, const float* __restrict__ W2,
    const float* __restrict__ s2, const float* __restrict__ b2,
    const float* __restrict__ W_lw, const float* __restrict__ x,
    const float* __restrict__ r_lw,
    float* __restrict__ psum, float* __restrict__ pn_part,
    unsigned short* __restrict__ Wlwt, unsigned short* __restrict__ xr)
{
    __shared__ __align__(16) unsigned short smem[6144];   // 12 KiB
    const int blk = blockIdx.x;
    const int t = threadIdx.x;
    if (blk < 320) {
        // fc2: A2 bf16, B = W2 [512][512] f32 k-major; fused psum/pn epilogue
        gemm_tile<1, 0, 1, 1, 4, 2, 1, 16, 512, NP, FF>(
            blk % 8, blk / 8, A2, nullptr, nullptr, nullptr, W2,
            s2, b2, nullptr, (void*)psum, pn_part, smem);
    } else if (blk < 960) {
        // W_lw [512][5120] f32 -> Wlwt[(c,f)][512] bf16 (col remap (f,c)->(c,f))
        unsigned short (*T)[65] = (unsigned short (*)[65])smem;
        const int bb = blk - 320;
        const int n0 = (bb % 80) * 64, k0 = (bb / 80) * 64;
#pragma unroll
        for (int p = 0; p < 4; ++p) {
            int kk = (t >> 4) + p * 16;
            int nn = (t & 15) * 4;
            float4 v = *(const float4*)(W_lw + (size_t)(k0 + kk) * OUTW + n0 + nn);
            T[nn + 0][kk] = f2bf(v.x);
            T[nn + 1][kk] = f2bf(v.y);
            T[nn + 2][kk] = f2bf(v.z);
            T[nn + 3][kk] = f2bf(v.w);
        }
        __syncthreads();
#pragma unroll
        for (int p = 0; p < 2; ++p) {
            int n = (t >> 3) + p * 32;
            int kg = t & 7;
            union { unsigned short us[8]; uint4 v; } o;
#pragma unroll
            for (int q = 0; q < 8; ++q) o.us[q] = T[n][kg * 8 + q];
            int gn = n0 + n;
            int dr = (gn % 10) * 512 + gn / 10;      // (f,c) -> (c,f)
            *(uint4*)(Wlwt + (size_t)dr * 512 + k0 + kg * 8) = o.v;
        }
    } else {
        // xr [512][512] bf16 = x * r_lw
        const int id = (blk - 960) * 256 + t;        // 32768 exact
        const int row = id >> 6, g = id & 63;
        const int mq = row >> 7;
        const float* xp = x + (size_t)row * 512 + g * 8;
        const float* rp = r_lw + (size_t)mq * 512 + g * 8;
        union { unsigned short us[8]; uint4 v; } o;
#pragma unroll
        for (int q = 0; q < 8; ++q) o.us[q] = f2bf(xp[q] * rp[q]);
        *(uint4*)(xr + (size_t)row * 512 + g * 8) = o.v;
    }
}

// ====== K3: z GEMM + fused zn/cr slot writes ======
__global__ __launch_bounds__(256) void k_phase3(
    const unsigned short* __restrict__ xr, const unsigned short* __restrict__ Wlwt,
    const float* __restrict__ s_lw, const float* __restrict__ psum,
    float* __restrict__ dist_part)
{
    __shared__ __align__(16) unsigned short smem[8192];   // 16 KiB
    gemm_tile<2, 0, 0, 2, 2, 2, 2, 16, 512, BB, OUTW>(
        blockIdx.x, blockIdx.y, xr, nullptr, nullptr, Wlwt, nullptr,
        s_lw, psum, nullptr, (void*)dist_part, nullptr, smem);
}

// ====== K4: reduce partials + exp ======
__global__ __launch_bounds__(256) void k_out(
    const float* __restrict__ dist_part, const float* __restrict__ pn_part,
    float* __restrict__ out)
{
    const int id = blockIdx.x * 256 + threadIdx.x;   // 5120 exact
    const int c = id % 10;
    const int mb = id / 10;
    const int mc = (mb >> 7) * 10 + c;
    const float* dp = dist_part + (size_t)id * 32;   // 16 slots x {zn,cr}
    float zn = 0.f, cr = 0.f;
#pragma unroll
    for (int q = 0; q < 16; ++q) {
        zn += dp[q * 2];
        cr += dp[q * 2 + 1];
    }
    float pnv = 0.f;
#pragma unroll
    for (int q = 0; q < 32; ++q) pnv += pn_part[mc * 32 + q];
    const float inv = 1.f / (2.f * (float)KK * (float)FF);
    out[id] = expf(-((float)KK * zn - 2.f * cr + pnv) * inv);
}

extern "C" void kernel_launch(void* const* d_in, const int* in_sizes, int n_in,
                              void* d_out, int out_size, void* d_ws, size_t ws_size,
                              hipStream_t stream) {
    const float* x     = (const float*)d_in[0];
    const float* noise = (const float*)d_in[1];
    const float* W_lw  = (const float*)d_in[2];
    const float* r_lw  = (const float*)d_in[3];
    const float* s_lw  = (const float*)d_in[4];
    const float* W1    = (const float*)d_in[5];
    const float* r1    = (const float*)d_in[6];
    const float* s1    = (const float*)d_in[7];
    const float* b1    = (const float*)d_in[8];
    const float* W2    = (const float*)d_in[9];
    const float* r2    = (const float*)d_in[10];
    const float* s2    = (const float*)d_in[11];
    const float* b2    = (const float*)d_in[12];
    float* out = (float*)d_out;

    char* base = (char*)d_ws;
    float* psum          = (float*)(base + 0);                 //    81,920 B
    float* pn_part       = (float*)(base + 81920);             //     5,120 B
    float* dist_part     = (float*)(base + 87040);             //   655,360 B
    unsigned short* A2   = (unsigned short*)(base + 742400);   // 1,310,720 B
    unsigned short* xr   = (unsigned short*)(base + 2053120);  //   524,288 B
    unsigned short* Wlwt = (unsigned short*)(base + 2577408);  // 5,242,880 B

    k_phase1<<<160, 256, 0, stream>>>(noise, r1, W1, s1, b1, r2, A2);
    k_phase2<<<1088, 256, 0, stream>>>(A2, W2, s2, b2, W_lw, x, r_lw,
                                       psum, pn_part, Wlwt, xr);
    k_phase3<<<dim3(80, 8), 256, 0, stream>>>(xr, Wlwt, s_lw, psum, dist_part);
    k_out<<<20, 256, 0, stream>>>(dist_part, pn_part, out);
}